// Round 1
// baseline (39.388 us; speedup 1.0000x reference)
//
#include <hip/hip_runtime.h>
#include <math.h>

#define N_TOK 8192
#define DIM   4096
#define NEXP  8
#define TPW   4   // tokens per wave

__global__ __launch_bounds__(256) void router_kernel(
    const float* __restrict__ x,   // [N_TOK, DIM]
    const float* __restrict__ w,   // [NEXP, DIM]
    float* __restrict__ out)       // [N_TOK*8] combine ++ [N_TOK*2] idx-as-float
{
    const int lane   = threadIdx.x & 63;
    const int waveid = threadIdx.x >> 6;           // 0..3
    const int group  = blockIdx.x * 4 + waveid;    // global wave id
    const int n0     = group * TPW;                // first token of this wave

    float acc[TPW][NEXP];
    #pragma unroll
    for (int t = 0; t < TPW; ++t)
        #pragma unroll
        for (int e = 0; e < NEXP; ++e) acc[t][e] = 0.0f;

    const int dbase = lane * 4;

    #pragma unroll 1
    for (int it = 0; it < DIM / 256; ++it) {
        const int d = it * 256 + dbase;

        float4 wv[NEXP];
        #pragma unroll
        for (int e = 0; e < NEXP; ++e)
            wv[e] = *(const float4*)(w + e * DIM + d);

        #pragma unroll
        for (int t = 0; t < TPW; ++t) {
            float4 xv = *(const float4*)(x + (size_t)(n0 + t) * DIM + d);
            #pragma unroll
            for (int e = 0; e < NEXP; ++e) {
                acc[t][e] = fmaf(xv.x, wv[e].x,
                            fmaf(xv.y, wv[e].y,
                            fmaf(xv.z, wv[e].z,
                            fmaf(xv.w, wv[e].w, acc[t][e]))));
            }
        }
    }

    // 64-lane butterfly reduction for each (token, expert) partial sum
    #pragma unroll
    for (int t = 0; t < TPW; ++t) {
        #pragma unroll
        for (int e = 0; e < NEXP; ++e) {
            float v = acc[t][e];
            #pragma unroll
            for (int off = 32; off >= 1; off >>= 1)
                v += __shfl_xor(v, off, 64);
            acc[t][e] = v;   // all lanes now hold the full logit
        }
    }

    // Epilogue: top-2 + renormalized softmax weights. Computed uniformly on
    // all lanes (compile-time indices only -> stays in VGPRs), lane 0 stores.
    #pragma unroll
    for (int t = 0; t < TPW; ++t) {
        // argmax (strict >, ascending scan => lowest index wins ties, like lax.top_k)
        float m1 = acc[t][0]; int i1 = 0;
        #pragma unroll
        for (int e = 1; e < NEXP; ++e)
            if (acc[t][e] > m1) { m1 = acc[t][e]; i1 = e; }
        // second max
        float m2 = -INFINITY; int i2 = 0;
        #pragma unroll
        for (int e = 0; e < NEXP; ++e)
            if (e != i1 && acc[t][e] > m2) { m2 = acc[t][e]; i2 = e; }

        // softmax denominator cancels in the top-k renormalization:
        // w1 = 1/(1+exp(l2-l1)), w2 = exp(l2-l1)/(1+exp(l2-l1))
        const float e2  = expf(m2 - m1);
        const float inv = 1.0f / (1.0f + e2);
        const float w1  = inv;
        const float w2  = e2 * inv;

        if (lane == 0) {
            const int n = n0 + t;
            float c[8];
            #pragma unroll
            for (int e = 0; e < 8; ++e)
                c[e] = (e == i1) ? w1 : ((e == i2) ? w2 : 0.0f);
            float4* cp = (float4*)(out + (size_t)n * 8);
            cp[0] = make_float4(c[0], c[1], c[2], c[3]);
            cp[1] = make_float4(c[4], c[5], c[6], c[7]);
            float* ip = out + (size_t)N_TOK * 8 + (size_t)n * 2;
            ip[0] = (float)i1;
            ip[1] = (float)i2;
        }
    }
}

extern "C" void kernel_launch(void* const* d_in, const int* in_sizes, int n_in,
                              void* d_out, int out_size, void* d_ws, size_t ws_size,
                              hipStream_t stream) {
    const float* x = (const float*)d_in[0];   // [8192, 4096] f32
    const float* w = (const float*)d_in[1];   // [8, 4096] f32
    float* out = (float*)d_out;               // 8192*8 + 8192*2 = 81920 f32

    // 8192 tokens / (4 waves/block * 4 tokens/wave) = 512 blocks
    dim3 grid(N_TOK / (4 * TPW));
    dim3 block(256);
    hipLaunchKernelGGL(router_kernel, grid, block, 0, stream, x, w, out);
}